// Round 2
// baseline (7274.927 us; speedup 1.0000x reference)
//
#include <hip/hip_runtime.h>
#include <hip/hip_bf16.h>

#define NUM_C 1024
#define EMB   512
#define HID   512
#define BATCH 64
#define SEQ   512

typedef short bf16x8 __attribute__((ext_vector_type(8)));
typedef float f32x4  __attribute__((ext_vector_type(4)));

__device__ __forceinline__ unsigned short f2bf(float x) {
    unsigned u = __float_as_uint(x);
    u += 0x7fffu + ((u >> 16) & 1u);
    return (unsigned short)(u >> 16);
}
__device__ __forceinline__ float uaf(unsigned u) { return __uint_as_float(u); }

// ---------------------------------------------------------------------------
__global__ __launch_bounds__(256) void f32_to_bf16(const float* __restrict__ src,
                                                   unsigned short* __restrict__ dst, int n) {
    int i = blockIdx.x * 256 + threadIdx.x;
    if (i < n) dst[i] = f2bf(src[i]);
}

// ---------------------------------------------------------------------------
// fp32 vector GEMM (NT): C[m][n] = sum_k A[m][k]*B[n][k] + b1[n] + b2[n]
// (proven in round 0; used only for the small emb_proj = emb @ Wx^T)
// ---------------------------------------------------------------------------
__global__ __launch_bounds__(256)
void gemm_nt_f32(const float* __restrict__ A, const float* __restrict__ B,
                 float* __restrict__ C, int M, int N, int K,
                 const float* __restrict__ bias1, const float* __restrict__ bias2) {
    __shared__ float As[64][33];
    __shared__ float Bs[64][33];

    const int n0 = blockIdx.x * 64;
    const int m0 = blockIdx.y * 64;
    const int tid = threadIdx.x;
    const int tx = tid & 15;
    const int ty = tid >> 4;

    float acc[4][4] = {{0.f}};

    for (int k0 = 0; k0 < K; k0 += 32) {
        #pragma unroll
        for (int i = 0; i < 2; ++i) {
            int f   = tid * 2 + i;
            int row = f >> 3;
            int kf  = f & 7;
            float4 va = *(const float4*)&A[(size_t)(m0 + row) * K + k0 + kf * 4];
            float4 vb = *(const float4*)&B[(size_t)(n0 + row) * K + k0 + kf * 4];
            As[row][kf * 4 + 0] = va.x; As[row][kf * 4 + 1] = va.y;
            As[row][kf * 4 + 2] = va.z; As[row][kf * 4 + 3] = va.w;
            Bs[row][kf * 4 + 0] = vb.x; Bs[row][kf * 4 + 1] = vb.y;
            Bs[row][kf * 4 + 2] = vb.z; Bs[row][kf * 4 + 3] = vb.w;
        }
        __syncthreads();
        #pragma unroll
        for (int kk = 0; kk < 32; ++kk) {
            float a[4], b[4];
            #pragma unroll
            for (int i = 0; i < 4; ++i) a[i] = As[ty * 4 + i][kk];
            #pragma unroll
            for (int j = 0; j < 4; ++j) b[j] = Bs[tx * 4 + j][kk];
            #pragma unroll
            for (int i = 0; i < 4; ++i)
                #pragma unroll
                for (int j = 0; j < 4; ++j)
                    acc[i][j] += a[i] * b[j];
        }
        __syncthreads();
    }

    float bb[4];
    #pragma unroll
    for (int j = 0; j < 4; ++j) {
        int n = n0 + tx * 4 + j;
        bb[j] = bias1[n] + bias2[n];
    }
    #pragma unroll
    for (int i = 0; i < 4; ++i) {
        size_t m = (size_t)(m0 + ty * 4 + i);
        float4 ov;
        ov.x = acc[i][0] + bb[0]; ov.y = acc[i][1] + bb[1];
        ov.z = acc[i][2] + bb[2]; ov.w = acc[i][3] + bb[3];
        *(float4*)&C[m * N + n0 + tx * 4] = ov;
    }
}

// ---------------------------------------------------------------------------
// Liquid-time-constant scan, 4 j-slices per batch, W-slice resident in LDS.
// grid = 256 blocks (b = bid&63, sl = bid>>6), 512 threads.
// LDS: W slice bf16 [128][64 uint4] XOR-swizzled (131072 B) + h bf16 (1024 B)
//      + partials (2048 B) = 134144 B -> exactly 1 block/CU, 256 co-resident.
// Cross-slice h exchange via hs_bf in global + per-batch monotonic counter.
// ---------------------------------------------------------------------------
__global__ __launch_bounds__(512)
void ltc_scan2(const int* __restrict__ q, const int* __restrict__ r,
               const float* __restrict__ emb_proj, const unsigned* __restrict__ Wbf,
               const float* __restrict__ tau, unsigned short* __restrict__ hs_bf,
               unsigned* __restrict__ cnt) {
    extern __shared__ char smem[];
    uint4*    Wl = (uint4*)smem;                    // [128][64], swizzled
    unsigned* hu = (unsigned*)(smem + 131072);      // 512 bf16 = 256 uints
    float*    ps = (float*)(smem + 131072 + 1024);  // [512]

    const int tid = threadIdx.x;
    const int b   = blockIdx.x & 63;
    const int sl  = blockIdx.x >> 6;
    const int j   = tid & 127;       // local output unit
    const int kq  = tid >> 7;        // k-quarter (128 k's each)
    const int kq16 = kq * 16;        // uint4 offset of this quarter
    const int swz = j & 7;

    // --- load resident W slice (rows sl*128..+127), bf16 pairs, swizzled ---
    #pragma unroll 4
    for (int p = 0; p < 16; ++p) {
        int flat = p * 512 + tid;            // uint4 index 0..8191
        int row  = flat >> 6;                // 0..127
        int i4   = flat & 63;                // 0..63
        uint4 v = *(const uint4*)(Wbf + (size_t)(sl * 128 + row) * 256 + i4 * 4);
        Wl[row * 64 + (i4 ^ (row & 7))] = v;
    }
    if (tid < 256) hu[tid] = 0;              // h = 0

    float rtau = 0.f, hprev = 0.f;
    if (tid < 128) rtau = 1.0f / tau[sl * 128 + tid];

    const int* qb = q + b * SEQ;
    const int* rb = r + b * SEQ;
    unsigned short* hsbfb = hs_bf + (size_t)b * SEQ * HID;
    const uint4* wq  = Wl + j * 64 + kq16;
    const uint4* hq  = (const uint4*)hu + kq16;
    unsigned* cw = &cnt[b * 16];             // 64B-strided counters
    __syncthreads();

    for (int s = 0; s < SEQ; ++s) {
        // issue gather early (independent of h) to hide latency under matvec
        float embp = 0.f;
        if (tid < 128) {
            int idx = qb[s] + NUM_C * rb[s];
            embp = emb_proj[(size_t)idx * HID + sl * 128 + tid];
        }

        // partial dot over this thread's k-quarter (128 MACs, bf16*bf16->f32)
        float a0 = 0.f, a1 = 0.f;
        #pragma unroll
        for (int i = 0; i < 16; ++i) {
            uint4 w  = wq[i ^ swz];
            uint4 hv = hq[i];                // wave-uniform -> broadcast
            a0 += uaf(w.x << 16) * uaf(hv.x << 16);
            a1 += uaf(w.x & 0xffff0000u) * uaf(hv.x & 0xffff0000u);
            a0 += uaf(w.y << 16) * uaf(hv.y << 16);
            a1 += uaf(w.y & 0xffff0000u) * uaf(hv.y & 0xffff0000u);
            a0 += uaf(w.z << 16) * uaf(hv.z << 16);
            a1 += uaf(w.z & 0xffff0000u) * uaf(hv.z & 0xffff0000u);
            a0 += uaf(w.w << 16) * uaf(hv.w << 16);
            a1 += uaf(w.w & 0xffff0000u) * uaf(hv.w & 0xffff0000u);
        }
        ps[tid] = a0 + a1;
        __syncthreads();                                   // A

        if (tid < 128) {
            float pre = embp + ((ps[tid] + ps[tid + 128]) + (ps[tid + 256] + ps[tid + 384]));
            float hn  = hprev + (tanhf(pre) - hprev) * rtau;
            hprev = hn;
            hsbfb[(size_t)s * HID + sl * 128 + tid] = f2bf(hn);
            __threadfence();                 // flush stores to device scope
        }
        __syncthreads();                                   // B

        if (tid == 0) {
            __hip_atomic_fetch_add(cw, 1u, __ATOMIC_RELEASE, __HIP_MEMORY_SCOPE_AGENT);
            unsigned target = 4u * (unsigned)(s + 1);
            while (__hip_atomic_load(cw, __ATOMIC_RELAXED, __HIP_MEMORY_SCOPE_AGENT) < target)
                __builtin_amdgcn_s_sleep(1);
            __threadfence();                 // acquire: invalidate stale cache
        }
        __syncthreads();                                   // C

        if (tid < 256)                       // pull full h (bf16) into LDS
            hu[tid] = ((const unsigned*)hsbfb)[s * 256 + tid];
        __syncthreads();                                   // D
    }
}

// ---------------------------------------------------------------------------
// Output GEMM: y = sigmoid(hs_bf @ Wo_bf^T + Wo_b), bf16 MFMA 16x16x32.
// 128x128 tile, 4 waves (2x2), each wave 4x4 fragments, BK=32.
// ---------------------------------------------------------------------------
__global__ __launch_bounds__(256)
void gemm_out_bf16(const unsigned short* __restrict__ A,   // [M][512]
                   const unsigned short* __restrict__ B,   // [1024][512]
                   const float* __restrict__ bias,
                   float* __restrict__ C, int M) {
    __shared__ __align__(16) unsigned short As[128 * 32];
    __shared__ __align__(16) unsigned short Bs[128 * 32];

    const int tid = threadIdx.x;
    const int n0 = blockIdx.x * 128;
    const int m0 = blockIdx.y * 128;
    const int w  = tid >> 6;
    const int l  = tid & 63;
    const int wr = w >> 1, wc = w & 1;
    const int lr = l & 15;       // frag row (A) / col (B,D)
    const int lq = l >> 4;       // k-octet / D row group

    f32x4 acc[4][4];
    #pragma unroll
    for (int i = 0; i < 4; ++i)
        #pragma unroll
        for (int jn = 0; jn < 4; ++jn)
            acc[i][jn] = (f32x4){0.f, 0.f, 0.f, 0.f};

    for (int k0 = 0; k0 < 512; k0 += 32) {
        #pragma unroll
        for (int p = 0; p < 2; ++p) {
            int flat = p * 256 + tid;        // 0..511
            int row  = flat >> 2;            // 0..127
            int c4   = flat & 3;
            *(uint4*)&As[row * 32 + c4 * 8] =
                *(const uint4*)&A[(size_t)(m0 + row) * 512 + k0 + c4 * 8];
            *(uint4*)&Bs[row * 32 + c4 * 8] =
                *(const uint4*)&B[(size_t)(n0 + row) * 512 + k0 + c4 * 8];
        }
        __syncthreads();

        bf16x8 af[4], bf[4];
        #pragma unroll
        for (int mf = 0; mf < 4; ++mf)
            af[mf] = *(const bf16x8*)&As[(wr * 64 + mf * 16 + lr) * 32 + lq * 8];
        #pragma unroll
        for (int nf = 0; nf < 4; ++nf)
            bf[nf] = *(const bf16x8*)&Bs[(wc * 64 + nf * 16 + lr) * 32 + lq * 8];

        #pragma unroll
        for (int mf = 0; mf < 4; ++mf)
            #pragma unroll
            for (int nf = 0; nf < 4; ++nf)
                acc[mf][nf] = __builtin_amdgcn_mfma_f32_16x16x32_bf16(
                    af[mf], bf[nf], acc[mf][nf], 0, 0, 0);
        __syncthreads();
    }

    #pragma unroll
    for (int mf = 0; mf < 4; ++mf) {
        #pragma unroll
        for (int nf = 0; nf < 4; ++nf) {
            int col = n0 + wc * 64 + nf * 16 + lr;       // D: col = lane&15
            float bb = bias[col];
            #pragma unroll
            for (int reg = 0; reg < 4; ++reg) {
                int rowm = m0 + wr * 64 + mf * 16 + lq * 4 + reg;  // row=(l>>4)*4+reg
                float v = acc[mf][nf][reg] + bb;
                C[(size_t)rowm * 1024 + col] = 1.0f / (1.0f + expf(-v));
            }
        }
    }
}

// ---------------------------------------------------------------------------
extern "C" void kernel_launch(void* const* d_in, const int* in_sizes, int n_in,
                              void* d_out, int out_size, void* d_ws, size_t ws_size,
                              hipStream_t stream) {
    const int*   q    = (const int*)d_in[0];
    const int*   r    = (const int*)d_in[1];
    const float* emb  = (const float*)d_in[2];
    const float* Wh_w = (const float*)d_in[3];
    const float* Wh_b = (const float*)d_in[4];
    const float* Wx_w = (const float*)d_in[5];
    const float* Wx_b = (const float*)d_in[6];
    const float* tau  = (const float*)d_in[7];
    const float* Wo_w = (const float*)d_in[8];
    const float* Wo_b = (const float*)d_in[9];
    float* out = (float*)d_out;

    char* ws = (char*)d_ws;
    float*          emb_proj = (float*)ws;                                    // 4 MiB
    unsigned short* Whbf     = (unsigned short*)(ws + (4u << 20));            // 512 KiB
    unsigned short* Wobf     = (unsigned short*)(ws + (4u << 20) + (512u << 10)); // 1 MiB
    unsigned short* hs_bf    = (unsigned short*)(ws + (4u << 20) + (512u << 10) + (1u << 20)); // 32 MiB
    unsigned*       cnt      = (unsigned*)(ws + (4u << 20) + (512u << 10) + (1u << 20) + (32u << 20)); // 4 KiB

    (void)hipFuncSetAttribute((const void*)ltc_scan2,
                              hipFuncAttributeMaxDynamicSharedMemorySize, 140 * 1024);

    // weight conversions (bf16)
    f32_to_bf16<<<(512 * 512) / 256, 256, 0, stream>>>(Wh_w, Whbf, 512 * 512);
    f32_to_bf16<<<(1024 * 512) / 256, 256, 0, stream>>>(Wo_w, Wobf, 1024 * 512);

    // emb_proj = emb @ Wx^T + Wx_b + Wh_b   (2048 distinct interaction rows)
    gemm_nt_f32<<<dim3(512 / 64, 2048 / 64), 256, 0, stream>>>(
        emb, Wx_w, emb_proj, 2048, 512, 512, Wx_b, Wh_b);

    // zero exchange counters (monotonic per launch)
    hipMemsetAsync(cnt, 0, 64 * 64, stream);

    // recurrence: 256 blocks (64 batches x 4 slices), 134144 B dynamic LDS
    ltc_scan2<<<256, 512, 134144, stream>>>(q, r, emb_proj, (const unsigned*)Whbf,
                                            tau, hs_bf, cnt);

    // y = sigmoid(hs @ Wo^T + Wo_b) via bf16 MFMA
    gemm_out_bf16<<<dim3(1024 / 128, (BATCH * SEQ) / 128), 256, 0, stream>>>(
        hs_bf, Wobf, Wo_b, out, BATCH * SEQ);
}

// Round 3
// 1235.292 us; speedup vs baseline: 5.8892x; 5.8892x over previous
//
#include <hip/hip_runtime.h>
#include <hip/hip_bf16.h>

#define NUM_C 1024
#define EMB   512
#define HID   512
#define BATCH 64
#define SEQ   512

typedef short bf16x8 __attribute__((ext_vector_type(8)));
typedef float f32x4  __attribute__((ext_vector_type(4)));

__device__ __forceinline__ unsigned short f2bf(float x) {
    unsigned u = __float_as_uint(x);
    u += 0x7fffu + ((u >> 16) & 1u);
    return (unsigned short)(u >> 16);
}
__device__ __forceinline__ float uaf(unsigned u) { return __uint_as_float(u); }

// ---------------------------------------------------------------------------
__global__ __launch_bounds__(256) void f32_to_bf16(const float* __restrict__ src,
                                                   unsigned short* __restrict__ dst, int n) {
    int i = blockIdx.x * 256 + threadIdx.x;
    if (i < n) dst[i] = f2bf(src[i]);
}

// ---------------------------------------------------------------------------
// fp32 vector GEMM (NT) for emb_proj = emb @ Wx^T + Wx_b + Wh_b
// ---------------------------------------------------------------------------
__global__ __launch_bounds__(256)
void gemm_nt_f32(const float* __restrict__ A, const float* __restrict__ B,
                 float* __restrict__ C, int M, int N, int K,
                 const float* __restrict__ bias1, const float* __restrict__ bias2) {
    __shared__ float As[64][33];
    __shared__ float Bs[64][33];

    const int n0 = blockIdx.x * 64;
    const int m0 = blockIdx.y * 64;
    const int tid = threadIdx.x;
    const int tx = tid & 15;
    const int ty = tid >> 4;

    float acc[4][4] = {{0.f}};

    for (int k0 = 0; k0 < K; k0 += 32) {
        #pragma unroll
        for (int i = 0; i < 2; ++i) {
            int f   = tid * 2 + i;
            int row = f >> 3;
            int kf  = f & 7;
            float4 va = *(const float4*)&A[(size_t)(m0 + row) * K + k0 + kf * 4];
            float4 vb = *(const float4*)&B[(size_t)(n0 + row) * K + k0 + kf * 4];
            As[row][kf * 4 + 0] = va.x; As[row][kf * 4 + 1] = va.y;
            As[row][kf * 4 + 2] = va.z; As[row][kf * 4 + 3] = va.w;
            Bs[row][kf * 4 + 0] = vb.x; Bs[row][kf * 4 + 1] = vb.y;
            Bs[row][kf * 4 + 2] = vb.z; Bs[row][kf * 4 + 3] = vb.w;
        }
        __syncthreads();
        #pragma unroll
        for (int kk = 0; kk < 32; ++kk) {
            float a[4], b[4];
            #pragma unroll
            for (int i = 0; i < 4; ++i) a[i] = As[ty * 4 + i][kk];
            #pragma unroll
            for (int j = 0; j < 4; ++j) b[j] = Bs[tx * 4 + j][kk];
            #pragma unroll
            for (int i = 0; i < 4; ++i)
                #pragma unroll
                for (int j = 0; j < 4; ++j)
                    acc[i][j] += a[i] * b[j];
        }
        __syncthreads();
    }

    float bb[4];
    #pragma unroll
    for (int j = 0; j < 4; ++j) {
        int n = n0 + tx * 4 + j;
        bb[j] = bias1[n] + bias2[n];
    }
    #pragma unroll
    for (int i = 0; i < 4; ++i) {
        size_t m = (size_t)(m0 + ty * 4 + i);
        float4 ov;
        ov.x = acc[i][0] + bb[0]; ov.y = acc[i][1] + bb[1];
        ov.z = acc[i][2] + bb[2]; ov.w = acc[i][3] + bb[3];
        *(float4*)&C[m * N + n0 + tx * 4] = ov;
    }
}

// ---------------------------------------------------------------------------
// LTC scan, 4 j-slices/batch, W-slice resident in LDS (bf16, XOR-swizzled).
// Cross-slice h exchange: sentinel-validated relaxed atomics through L2.
//   - hs pre-filled with 0x7F7F bytes; legit h has |h|<=1 -> halfword 0x7F7F
//     (exp=254) is impossible -> each uint (2 bf16) is self-validating.
//   - writer: one relaxed agent atomic store per uint (written once per launch)
//   - reader: poll word until low half != 0x7F7F, unpack to f32 LDS.
// grid=256 (b=bid&63, sl=bid>>6 -> partners on same XCD), 512 thr, 1 blk/CU.
// LDS: W 131072 | hf f32[512] 2048 | ps f32[512] 2048 | idx i32[512] 2048.
// ---------------------------------------------------------------------------
__global__ __launch_bounds__(512)
void ltc_scan3(const int* __restrict__ q, const int* __restrict__ r,
               const float* __restrict__ emb_proj, const unsigned* __restrict__ Wbf,
               const float* __restrict__ tau, unsigned short* __restrict__ hs_bf) {
    extern __shared__ char smem[];
    uint4* Wl  = (uint4*)smem;                         // [128][64] swizzled
    float* hf  = (float*)(smem + 131072);              // h as f32 [512]
    float* ps  = (float*)(smem + 131072 + 2048);       // partials [512]
    int*   idl = (int*)(smem + 131072 + 4096);         // idx per step [512]

    const int tid = threadIdx.x;
    const int b   = blockIdx.x & 63;
    const int sl  = blockIdx.x >> 6;
    const int j   = tid & 127;
    const int kq  = tid >> 7;
    const int kq16 = kq * 16;
    const int swz  = j & 7;

    // resident W slice (rows sl*128..+127), bf16, swizzled
    #pragma unroll 4
    for (int p = 0; p < 16; ++p) {
        int flat = p * 512 + tid;
        int row  = flat >> 6;
        int i4   = flat & 63;
        uint4 v = *(const uint4*)(Wbf + (size_t)(sl * 128 + row) * 256 + i4 * 4);
        Wl[row * 64 + (i4 ^ (row & 7))] = v;
    }
    hf[tid] = 0.f;
    idl[tid] = q[b * SEQ + tid] + NUM_C * r[b * SEQ + tid];

    float rtau = 0.f, hprev = 0.f;
    if (tid < 128) rtau = 1.0f / tau[sl * 128 + tid];

    unsigned* hsw = (unsigned*)(hs_bf + (size_t)b * SEQ * HID);
    const uint4*  wq  = Wl + j * 64 + kq16;
    const float4* hqf = (const float4*)hf + kq * 32;
    __syncthreads();

    for (int s = 0; s < SEQ; ++s) {
        float embp = 0.f;
        if (tid < 128)
            embp = emb_proj[(size_t)idl[s] * HID + sl * 128 + tid];

        // partial dot over this thread's k-quarter (128 MACs)
        float a0 = 0.f, a1 = 0.f;
        #pragma unroll
        for (int i = 0; i < 16; ++i) {
            uint4 w  = wq[i ^ swz];
            float4 h0 = hqf[2 * i];
            float4 h1 = hqf[2 * i + 1];
            a0 += uaf(w.x << 16) * h0.x; a1 += uaf(w.x & 0xffff0000u) * h0.y;
            a0 += uaf(w.y << 16) * h0.z; a1 += uaf(w.y & 0xffff0000u) * h0.w;
            a0 += uaf(w.z << 16) * h1.x; a1 += uaf(w.z & 0xffff0000u) * h1.y;
            a0 += uaf(w.w << 16) * h1.z; a1 += uaf(w.w & 0xffff0000u) * h1.w;
        }
        ps[tid] = a0 + a1;
        __syncthreads();                                   // A: ps ready, hf reads done

        if (tid < 128) {
            float pre = embp + ((ps[tid] + ps[tid + 128]) + (ps[tid + 256] + ps[tid + 384]));
            float hn  = hprev + (tanhf(pre) - hprev) * rtau;
            hprev = hn;
            hf[sl * 128 + tid] = hn;                       // own slice, f32
            unsigned us = f2bf(hn);
            unsigned other = (unsigned)__shfl_xor((int)us, 1);
            if ((tid & 1) == 0) {
                unsigned word = us | (other << 16);
                __hip_atomic_store(&hsw[s * 256 + sl * 64 + (tid >> 1)], word,
                                   __ATOMIC_RELAXED, __HIP_MEMORY_SCOPE_AGENT);
            }
        }
        __syncthreads();                                   // B: store issued before polls

        if (tid < 192) {
            int u = tid + (tid >= sl * 64 ? 64 : 0);       // skip own slice
            unsigned w;
            while (((w = __hip_atomic_load(&hsw[s * 256 + u], __ATOMIC_RELAXED,
                                           __HIP_MEMORY_SCOPE_AGENT)) & 0xffffu) == 0x7f7fu)
                __builtin_amdgcn_s_sleep(1);
            hf[2 * u]     = uaf(w << 16);
            hf[2 * u + 1] = uaf(w & 0xffff0000u);
        }
        __syncthreads();                                   // C: hf complete for next step
    }
}

// ---------------------------------------------------------------------------
// Output GEMM: y = sigmoid(hs_bf @ Wo_bf^T + Wo_b), bf16 MFMA 16x16x32.
// ---------------------------------------------------------------------------
__global__ __launch_bounds__(256)
void gemm_out_bf16(const unsigned short* __restrict__ A,   // [M][512]
                   const unsigned short* __restrict__ B,   // [1024][512]
                   const float* __restrict__ bias,
                   float* __restrict__ C, int M) {
    __shared__ __align__(16) unsigned short As[128 * 32];
    __shared__ __align__(16) unsigned short Bs[128 * 32];

    const int tid = threadIdx.x;
    const int n0 = blockIdx.x * 128;
    const int m0 = blockIdx.y * 128;
    const int w  = tid >> 6;
    const int l  = tid & 63;
    const int wr = w >> 1, wc = w & 1;
    const int lr = l & 15;
    const int lq = l >> 4;

    f32x4 acc[4][4];
    #pragma unroll
    for (int i = 0; i < 4; ++i)
        #pragma unroll
        for (int jn = 0; jn < 4; ++jn)
            acc[i][jn] = (f32x4){0.f, 0.f, 0.f, 0.f};

    for (int k0 = 0; k0 < 512; k0 += 32) {
        #pragma unroll
        for (int p = 0; p < 2; ++p) {
            int flat = p * 256 + tid;
            int row  = flat >> 2;
            int c4   = flat & 3;
            *(uint4*)&As[row * 32 + c4 * 8] =
                *(const uint4*)&A[(size_t)(m0 + row) * 512 + k0 + c4 * 8];
            *(uint4*)&Bs[row * 32 + c4 * 8] =
                *(const uint4*)&B[(size_t)(n0 + row) * 512 + k0 + c4 * 8];
        }
        __syncthreads();

        bf16x8 af[4], bf[4];
        #pragma unroll
        for (int mf = 0; mf < 4; ++mf)
            af[mf] = *(const bf16x8*)&As[(wr * 64 + mf * 16 + lr) * 32 + lq * 8];
        #pragma unroll
        for (int nf = 0; nf < 4; ++nf)
            bf[nf] = *(const bf16x8*)&Bs[(wc * 64 + nf * 16 + lr) * 32 + lq * 8];

        #pragma unroll
        for (int mf = 0; mf < 4; ++mf)
            #pragma unroll
            for (int nf = 0; nf < 4; ++nf)
                acc[mf][nf] = __builtin_amdgcn_mfma_f32_16x16x32_bf16(
                    af[mf], bf[nf], acc[mf][nf], 0, 0, 0);
        __syncthreads();
    }

    #pragma unroll
    for (int mf = 0; mf < 4; ++mf) {
        #pragma unroll
        for (int nf = 0; nf < 4; ++nf) {
            int col = n0 + wc * 64 + nf * 16 + lr;
            float bb = bias[col];
            #pragma unroll
            for (int reg = 0; reg < 4; ++reg) {
                int rowm = m0 + wr * 64 + mf * 16 + lq * 4 + reg;
                float v = acc[mf][nf][reg] + bb;
                C[(size_t)rowm * 1024 + col] = 1.0f / (1.0f + expf(-v));
            }
        }
    }
}

// ---------------------------------------------------------------------------
extern "C" void kernel_launch(void* const* d_in, const int* in_sizes, int n_in,
                              void* d_out, int out_size, void* d_ws, size_t ws_size,
                              hipStream_t stream) {
    const int*   q    = (const int*)d_in[0];
    const int*   r    = (const int*)d_in[1];
    const float* emb  = (const float*)d_in[2];
    const float* Wh_w = (const float*)d_in[3];
    const float* Wh_b = (const float*)d_in[4];
    const float* Wx_w = (const float*)d_in[5];
    const float* Wx_b = (const float*)d_in[6];
    const float* tau  = (const float*)d_in[7];
    const float* Wo_w = (const float*)d_in[8];
    const float* Wo_b = (const float*)d_in[9];
    float* out = (float*)d_out;

    char* ws = (char*)d_ws;
    float*          emb_proj = (float*)ws;                                        // 4 MiB
    unsigned short* Whbf     = (unsigned short*)(ws + (4u << 20));                // 512 KiB
    unsigned short* Wobf     = (unsigned short*)(ws + (4u << 20) + (512u << 10)); // 1 MiB
    unsigned short* hs_bf    = (unsigned short*)(ws + (4u << 20) + (512u << 10) + (1u << 20)); // 32 MiB

    (void)hipFuncSetAttribute((const void*)ltc_scan3,
                              hipFuncAttributeMaxDynamicSharedMemorySize, 140 * 1024);

    // sentinel-fill hs (0x7F7F halfwords are unreachable for |h|<=1 bf16)
    hipMemsetAsync(hs_bf, 0x7F, (size_t)BATCH * SEQ * HID * 2, stream);

    // weight conversions (bf16)
    f32_to_bf16<<<(512 * 512) / 256, 256, 0, stream>>>(Wh_w, Whbf, 512 * 512);
    f32_to_bf16<<<(1024 * 512) / 256, 256, 0, stream>>>(Wo_w, Wobf, 1024 * 512);

    // emb_proj = emb @ Wx^T + Wx_b + Wh_b (2048 distinct interaction rows)
    gemm_nt_f32<<<dim3(512 / 64, 2048 / 64), 256, 0, stream>>>(
        emb, Wx_w, emb_proj, 2048, 512, 512, Wx_b, Wh_b);

    // recurrence: 256 blocks (64 batches x 4 slices), 137216 B dynamic LDS
    ltc_scan3<<<256, 512, 137216, stream>>>(q, r, emb_proj, (const unsigned*)Whbf,
                                            tau, hs_bf);

    // y = sigmoid(hs @ Wo^T + Wo_b) via bf16 MFMA
    gemm_out_bf16<<<dim3(1024 / 128, (BATCH * SEQ) / 128), 256, 0, stream>>>(
        hs_bf, Wobf, Wo_b, out, BATCH * SEQ);
}

// Round 4
// 1162.291 us; speedup vs baseline: 6.2591x; 1.0628x over previous
//
#include <hip/hip_runtime.h>
#include <hip/hip_bf16.h>

#define NUM_C 1024
#define EMB   512
#define HID   512
#define BATCH 64
#define SEQ   512

typedef short bf16x8 __attribute__((ext_vector_type(8)));
typedef float f32x4  __attribute__((ext_vector_type(4)));

__device__ __forceinline__ unsigned short f2bf(float x) {
    unsigned u = __float_as_uint(x);
    u += 0x7fffu + ((u >> 16) & 1u);
    return (unsigned short)(u >> 16);
}
__device__ __forceinline__ float uaf(unsigned u) { return __uint_as_float(u); }

// ---------------------------------------------------------------------------
__global__ __launch_bounds__(256) void f32_to_bf16(const float* __restrict__ src,
                                                   unsigned short* __restrict__ dst, int n) {
    int i = blockIdx.x * 256 + threadIdx.x;
    if (i < n) dst[i] = f2bf(src[i]);
}

// ---------------------------------------------------------------------------
// fp32 vector GEMM (NT) for emb_proj = emb @ Wx^T + Wx_b + Wh_b
// ---------------------------------------------------------------------------
__global__ __launch_bounds__(256)
void gemm_nt_f32(const float* __restrict__ A, const float* __restrict__ B,
                 float* __restrict__ C, int M, int N, int K,
                 const float* __restrict__ bias1, const float* __restrict__ bias2) {
    __shared__ float As[64][33];
    __shared__ float Bs[64][33];

    const int n0 = blockIdx.x * 64;
    const int m0 = blockIdx.y * 64;
    const int tid = threadIdx.x;
    const int tx = tid & 15;
    const int ty = tid >> 4;

    float acc[4][4] = {{0.f}};

    for (int k0 = 0; k0 < K; k0 += 32) {
        #pragma unroll
        for (int i = 0; i < 2; ++i) {
            int f   = tid * 2 + i;
            int row = f >> 3;
            int kf  = f & 7;
            float4 va = *(const float4*)&A[(size_t)(m0 + row) * K + k0 + kf * 4];
            float4 vb = *(const float4*)&B[(size_t)(n0 + row) * K + k0 + kf * 4];
            As[row][kf * 4 + 0] = va.x; As[row][kf * 4 + 1] = va.y;
            As[row][kf * 4 + 2] = va.z; As[row][kf * 4 + 3] = va.w;
            Bs[row][kf * 4 + 0] = vb.x; Bs[row][kf * 4 + 1] = vb.y;
            Bs[row][kf * 4 + 2] = vb.z; Bs[row][kf * 4 + 3] = vb.w;
        }
        __syncthreads();
        #pragma unroll
        for (int kk = 0; kk < 32; ++kk) {
            float a[4], b[4];
            #pragma unroll
            for (int i = 0; i < 4; ++i) a[i] = As[ty * 4 + i][kk];
            #pragma unroll
            for (int j = 0; j < 4; ++j) b[j] = Bs[tx * 4 + j][kk];
            #pragma unroll
            for (int i = 0; i < 4; ++i)
                #pragma unroll
                for (int j = 0; j < 4; ++j)
                    acc[i][j] += a[i] * b[j];
        }
        __syncthreads();
    }

    float bb[4];
    #pragma unroll
    for (int j = 0; j < 4; ++j) {
        int n = n0 + tx * 4 + j;
        bb[j] = bias1[n] + bias2[n];
    }
    #pragma unroll
    for (int i = 0; i < 4; ++i) {
        size_t m = (size_t)(m0 + ty * 4 + i);
        float4 ov;
        ov.x = acc[i][0] + bb[0]; ov.y = acc[i][1] + bb[1];
        ov.z = acc[i][2] + bb[2]; ov.w = acc[i][3] + bb[3];
        *(float4*)&C[m * N + n0 + tx * 4] = ov;
    }
}

// ---------------------------------------------------------------------------
// poll one exchange word (2 bf16) until it's no longer the 0x7F7F sentinel,
// then unpack into hf.  |h|<=1 -> halfword 0x7F7F (exp=254) is unreachable.
// ---------------------------------------------------------------------------
__device__ __forceinline__ void poll_word(unsigned* __restrict__ hsw,
                                          float* __restrict__ hf,
                                          int s, int sl, int u) {
    int p  = u >> 5;  p += (p >= sl);       // partner slice (skip own)
    int wi = p * 32 + (u & 31);
    unsigned w;
    while (((w = __hip_atomic_load(&hsw[s * 256 + wi], __ATOMIC_RELAXED,
                                   __HIP_MEMORY_SCOPE_AGENT)) & 0xffffu) == 0x7f7fu)
        __builtin_amdgcn_s_sleep(1);
    hf[2 * wi]     = uaf(w << 16);
    hf[2 * wi + 1] = uaf(w & 0xffff0000u);
}

// ---------------------------------------------------------------------------
// LTC scan v4: W in REGISTERS (f32), 8 slices x 64 rows, 2 batches per block.
// grid = 256 (sl = bid>>5, batch pair bp = bid&31 -> batches 2bp, 2bp+1).
// Per step:  mvA | sync | finishA(w0) || mvB(all) | sync |
//            finishB(w7) || pollA(w1-3) || pollB(w4-6) | sync
// Exchange (sentinel-validated relaxed atomics, same-XCD partners) hides
// under the other batch's matvec.  96KB dummy LDS forces 1 block/CU.
// ---------------------------------------------------------------------------
__global__ __launch_bounds__(512, 2)
void ltc_scan4(const int* __restrict__ q, const int* __restrict__ r,
               const float* __restrict__ emb_proj, const float* __restrict__ Wh,
               const float* __restrict__ tau, unsigned short* __restrict__ hs_bf) {
    extern __shared__ char smem[];
    float* hfA = (float*)smem;            // h (f32) batch A [512]
    float* hfB = hfA + 512;               // h (f32) batch B [512]
    float* psA = hfB + 512;               // partials A [512]
    float* psB = psA + 512;               // partials B [512]
    int*   idA = (int*)(psB + 512);       // gather idx A [512]
    int*   idB = idA + 512;               // gather idx B [512]

    const int tid = threadIdx.x;
    const int sl  = blockIdx.x >> 5;      // slice 0..7 (owns h rows sl*64..+63)
    const int bp  = blockIdx.x & 31;      // batch pair
    const int bA  = bp * 2, bB = bA + 1;
    const int j   = tid & 63;             // row within slice
    const int kq  = tid >> 6;             // k-chunk == wave id (64 k's each)

    // W chunk -> registers: row sl*64+j, cols kq*64..+63 (fp32, 64 VGPRs)
    float4 wr_[16];
    const float* wrow = Wh + (size_t)(sl * 64 + j) * 512 + kq * 64;
    #pragma unroll
    for (int i = 0; i < 16; ++i)
        wr_[i] = *(const float4*)(wrow + i * 4);

    hfA[tid] = 0.f; hfB[tid] = 0.f;
    idA[tid] = q[bA * SEQ + tid] + NUM_C * r[bA * SEQ + tid];
    idB[tid] = q[bB * SEQ + tid] + NUM_C * r[bB * SEQ + tid];

    float rtauA = 0.f, rtauB = 0.f, hprevA = 0.f, hprevB = 0.f;
    if (tid < 64)   rtauA = 1.0f / tau[sl * 64 + tid];
    if (tid >= 448) rtauB = 1.0f / tau[sl * 64 + (tid - 448)];

    unsigned* hswA = (unsigned*)(hs_bf + (size_t)bA * SEQ * HID);
    unsigned* hswB = (unsigned*)(hs_bf + (size_t)bB * SEQ * HID);
    const float4* hqA = (const float4*)hfA + kq * 16;
    const float4* hqB = (const float4*)hfB + kq * 16;
    __syncthreads();

    for (int s = 0; s < SEQ; ++s) {
        // issue gathers early (independent of h)
        float embpA = 0.f, embpB = 0.f;
        if (tid < 64)   embpA = emb_proj[(size_t)idA[s] * HID + sl * 64 + tid];
        if (tid >= 448) embpB = emb_proj[(size_t)idB[s] * HID + sl * 64 + (tid - 448)];

        // ---- phase 1: matvec A (all waves; W from regs, h broadcast) ----
        {
            float a0 = 0.f, a1 = 0.f, a2 = 0.f, a3 = 0.f;
            #pragma unroll
            for (int i = 0; i < 16; ++i) {
                float4 hv = hqA[i];
                a0 += wr_[i].x * hv.x; a1 += wr_[i].y * hv.y;
                a2 += wr_[i].z * hv.z; a3 += wr_[i].w * hv.w;
            }
            psA[tid] = (a0 + a1) + (a2 + a3);
        }
        __syncthreads();                                           // 1

        // ---- phase 2: finish A (wave 0)  ||  matvec B (all waves) ----
        if (tid < 64) {
            float pre = embpA;
            #pragma unroll
            for (int m = 0; m < 8; ++m) pre += psA[tid + 64 * m];
            float hn = hprevA + (tanhf(pre) - hprevA) * rtauA;
            hprevA = hn;
            hfA[sl * 64 + tid] = hn;                               // own slice f32
            unsigned us = f2bf(hn);
            unsigned ot = (unsigned)__shfl_xor((int)us, 1);
            if (!(tid & 1))
                __hip_atomic_store(&hswA[s * 256 + sl * 32 + (tid >> 1)],
                                   us | (ot << 16),
                                   __ATOMIC_RELAXED, __HIP_MEMORY_SCOPE_AGENT);
        }
        {
            float a0 = 0.f, a1 = 0.f, a2 = 0.f, a3 = 0.f;
            #pragma unroll
            for (int i = 0; i < 16; ++i) {
                float4 hv = hqB[i];
                a0 += wr_[i].x * hv.x; a1 += wr_[i].y * hv.y;
                a2 += wr_[i].z * hv.z; a3 += wr_[i].w * hv.w;
            }
            psB[tid] = (a0 + a1) + (a2 + a3);
        }
        __syncthreads();                                           // 2

        // ---- phase 3: finish B (wave 7) || poll A (w1-3) || poll B (w4-6) ----
        if (tid >= 448) {
            int jb = tid - 448;
            float pre = embpB;
            #pragma unroll
            for (int m = 0; m < 8; ++m) pre += psB[jb + 64 * m];
            float hn = hprevB + (tanhf(pre) - hprevB) * rtauB;
            hprevB = hn;
            hfB[sl * 64 + jb] = hn;
            unsigned us = f2bf(hn);
            unsigned ot = (unsigned)__shfl_xor((int)us, 1);
            if (!(jb & 1))
                __hip_atomic_store(&hswB[s * 256 + sl * 32 + (jb >> 1)],
                                   us | (ot << 16),
                                   __ATOMIC_RELAXED, __HIP_MEMORY_SCOPE_AGENT);
        } else if (s != SEQ - 1) {
            if (tid >= 64 && tid < 256) {          // waves 1-3: batch A words
                int u = tid - 64;                  // 0..191
                poll_word(hswA, hfA, s, sl, u);
                if (u < 32) poll_word(hswA, hfA, s, sl, 192 + u);
            } else if (tid >= 256) {               // waves 4-6: batch B words
                int u = tid - 256;                 // 0..191
                poll_word(hswB, hfB, s, sl, u);
                if (u < 32) poll_word(hswB, hfB, s, sl, 192 + u);
            }
        }
        __syncthreads();                                           // 3
    }
}

// ---------------------------------------------------------------------------
// Output GEMM: y = sigmoid(hs_bf @ Wo_bf^T + Wo_b), bf16 MFMA 16x16x32.
// ---------------------------------------------------------------------------
__global__ __launch_bounds__(256)
void gemm_out_bf16(const unsigned short* __restrict__ A,   // [M][512]
                   const unsigned short* __restrict__ B,   // [1024][512]
                   const float* __restrict__ bias,
                   float* __restrict__ C, int M) {
    __shared__ __align__(16) unsigned short As[128 * 32];
    __shared__ __align__(16) unsigned short Bs[128 * 32];

    const int tid = threadIdx.x;
    const int n0 = blockIdx.x * 128;
    const int m0 = blockIdx.y * 128;
    const int w  = tid >> 6;
    const int l  = tid & 63;
    const int wr = w >> 1, wc = w & 1;
    const int lr = l & 15;
    const int lq = l >> 4;

    f32x4 acc[4][4];
    #pragma unroll
    for (int i = 0; i < 4; ++i)
        #pragma unroll
        for (int jn = 0; jn < 4; ++jn)
            acc[i][jn] = (f32x4){0.f, 0.f, 0.f, 0.f};

    for (int k0 = 0; k0 < 512; k0 += 32) {
        #pragma unroll
        for (int p = 0; p < 2; ++p) {
            int flat = p * 256 + tid;
            int row  = flat >> 2;
            int c4   = flat & 3;
            *(uint4*)&As[row * 32 + c4 * 8] =
                *(const uint4*)&A[(size_t)(m0 + row) * 512 + k0 + c4 * 8];
            *(uint4*)&Bs[row * 32 + c4 * 8] =
                *(const uint4*)&B[(size_t)(n0 + row) * 512 + k0 + c4 * 8];
        }
        __syncthreads();

        bf16x8 af[4], bf[4];
        #pragma unroll
        for (int mf = 0; mf < 4; ++mf)
            af[mf] = *(const bf16x8*)&As[(wr * 64 + mf * 16 + lr) * 32 + lq * 8];
        #pragma unroll
        for (int nf = 0; nf < 4; ++nf)
            bf[nf] = *(const bf16x8*)&Bs[(wc * 64 + nf * 16 + lr) * 32 + lq * 8];

        #pragma unroll
        for (int mf = 0; mf < 4; ++mf)
            #pragma unroll
            for (int nf = 0; nf < 4; ++nf)
                acc[mf][nf] = __builtin_amdgcn_mfma_f32_16x16x32_bf16(
                    af[mf], bf[nf], acc[mf][nf], 0, 0, 0);
        __syncthreads();
    }

    #pragma unroll
    for (int mf = 0; mf < 4; ++mf) {
        #pragma unroll
        for (int nf = 0; nf < 4; ++nf) {
            int col = n0 + wc * 64 + nf * 16 + lr;
            float bb = bias[col];
            #pragma unroll
            for (int reg = 0; reg < 4; ++reg) {
                int rowm = m0 + wr * 64 + mf * 16 + lq * 4 + reg;
                float v = acc[mf][nf][reg] + bb;
                C[(size_t)rowm * 1024 + col] = 1.0f / (1.0f + expf(-v));
            }
        }
    }
}

// ---------------------------------------------------------------------------
extern "C" void kernel_launch(void* const* d_in, const int* in_sizes, int n_in,
                              void* d_out, int out_size, void* d_ws, size_t ws_size,
                              hipStream_t stream) {
    const int*   q    = (const int*)d_in[0];
    const int*   r    = (const int*)d_in[1];
    const float* emb  = (const float*)d_in[2];
    const float* Wh_w = (const float*)d_in[3];
    const float* Wh_b = (const float*)d_in[4];
    const float* Wx_w = (const float*)d_in[5];
    const float* Wx_b = (const float*)d_in[6];
    const float* tau  = (const float*)d_in[7];
    const float* Wo_w = (const float*)d_in[8];
    const float* Wo_b = (const float*)d_in[9];
    float* out = (float*)d_out;

    char* ws = (char*)d_ws;
    float*          emb_proj = (float*)ws;                                        // 4 MiB
    unsigned short* Wobf     = (unsigned short*)(ws + (4u << 20));                // 1 MiB
    unsigned short* hs_bf    = (unsigned short*)(ws + (5u << 20));                // 32 MiB

    (void)hipFuncSetAttribute((const void*)ltc_scan4,
                              hipFuncAttributeMaxDynamicSharedMemorySize, 131072);

    // sentinel-fill hs (0x7F7F halfwords unreachable for |h|<=1 bf16)
    hipMemsetAsync(hs_bf, 0x7F, (size_t)BATCH * SEQ * HID * 2, stream);

    // Wo -> bf16 for the MFMA output GEMM
    f32_to_bf16<<<(1024 * 512) / 256, 256, 0, stream>>>(Wo_w, Wobf, 1024 * 512);

    // emb_proj = emb @ Wx^T + Wx_b + Wh_b (2048 distinct interaction rows)
    gemm_nt_f32<<<dim3(512 / 64, 2048 / 64), 256, 0, stream>>>(
        emb, Wx_w, emb_proj, 2048, 512, 512, Wx_b, Wh_b);

    // recurrence: 256 blocks (8 slices x 32 batch-pairs); 96KB LDS -> 1 blk/CU
    ltc_scan4<<<256, 512, 98304, stream>>>(q, r, emb_proj, Wh_w, tau, hs_bf);

    // y = sigmoid(hs @ Wo^T + Wo_b) via bf16 MFMA
    gemm_out_bf16<<<dim3(1024 / 128, (BATCH * SEQ) / 128), 256, 0, stream>>>(
        hs_bf, Wobf, Wo_b, out, BATCH * SEQ);
}

// Round 5
// 945.979 us; speedup vs baseline: 7.6904x; 1.2287x over previous
//
#include <hip/hip_runtime.h>
#include <hip/hip_bf16.h>

#define NUM_C 1024
#define EMB   512
#define HID   512
#define BATCH 64
#define SEQ   512

typedef short bf16x8 __attribute__((ext_vector_type(8)));
typedef float f32x4  __attribute__((ext_vector_type(4)));

__device__ __forceinline__ unsigned short f2bf(float x) {
    unsigned u = __float_as_uint(x);
    u += 0x7fffu + ((u >> 16) & 1u);
    return (unsigned short)(u >> 16);
}
__device__ __forceinline__ float uaf(unsigned u) { return __uint_as_float(u); }

// fast tanh: exact at +-inf, ~1e-7 rel err, no branches
__device__ __forceinline__ float ftanh(float x) {
    float e = __expf(2.f * x);
    return 1.f - 2.f / (e + 1.f);
}

// ---------------------------------------------------------------------------
__global__ __launch_bounds__(256) void f32_to_bf16(const float* __restrict__ src,
                                                   unsigned short* __restrict__ dst, int n) {
    int i = blockIdx.x * 256 + threadIdx.x;
    if (i < n) dst[i] = f2bf(src[i]);
}

// ---------------------------------------------------------------------------
// fp32 vector GEMM (NT) for emb_proj = emb @ Wx^T + Wx_b + Wh_b
// ---------------------------------------------------------------------------
__global__ __launch_bounds__(256)
void gemm_nt_f32(const float* __restrict__ A, const float* __restrict__ B,
                 float* __restrict__ C, int M, int N, int K,
                 const float* __restrict__ bias1, const float* __restrict__ bias2) {
    __shared__ float As[64][33];
    __shared__ float Bs[64][33];

    const int n0 = blockIdx.x * 64;
    const int m0 = blockIdx.y * 64;
    const int tid = threadIdx.x;
    const int tx = tid & 15;
    const int ty = tid >> 4;

    float acc[4][4] = {{0.f}};

    for (int k0 = 0; k0 < K; k0 += 32) {
        #pragma unroll
        for (int i = 0; i < 2; ++i) {
            int f   = tid * 2 + i;
            int row = f >> 3;
            int kf  = f & 7;
            float4 va = *(const float4*)&A[(size_t)(m0 + row) * K + k0 + kf * 4];
            float4 vb = *(const float4*)&B[(size_t)(n0 + row) * K + k0 + kf * 4];
            As[row][kf * 4 + 0] = va.x; As[row][kf * 4 + 1] = va.y;
            As[row][kf * 4 + 2] = va.z; As[row][kf * 4 + 3] = va.w;
            Bs[row][kf * 4 + 0] = vb.x; Bs[row][kf * 4 + 1] = vb.y;
            Bs[row][kf * 4 + 2] = vb.z; Bs[row][kf * 4 + 3] = vb.w;
        }
        __syncthreads();
        #pragma unroll
        for (int kk = 0; kk < 32; ++kk) {
            float a[4], b[4];
            #pragma unroll
            for (int i = 0; i < 4; ++i) a[i] = As[ty * 4 + i][kk];
            #pragma unroll
            for (int j = 0; j < 4; ++j) b[j] = Bs[tx * 4 + j][kk];
            #pragma unroll
            for (int i = 0; i < 4; ++i)
                #pragma unroll
                for (int j = 0; j < 4; ++j)
                    acc[i][j] += a[i] * b[j];
        }
        __syncthreads();
    }

    float bb[4];
    #pragma unroll
    for (int j = 0; j < 4; ++j) {
        int n = n0 + tx * 4 + j;
        bb[j] = bias1[n] + bias2[n];
    }
    #pragma unroll
    for (int i = 0; i < 4; ++i) {
        size_t m = (size_t)(m0 + ty * 4 + i);
        float4 ov;
        ov.x = acc[i][0] + bb[0]; ov.y = acc[i][1] + bb[1];
        ov.z = acc[i][2] + bb[2]; ov.w = acc[i][3] + bb[3];
        *(float4*)&C[m * N + n0 + tx * 4] = ov;
    }
}

// ---------------------------------------------------------------------------
// LTC scan v5: slice-aligned poll+mac fusion.
// 8 slices x 64 rows, W f32 in regs (64 VGPR), 2 batches per block,
// grid = 256 (sl = bid>>5, bp = bid&31 -> batches 2bp,2bp+1; partner blocks
// stride 32 -> same XCD).  Wave w's k-chunk == slice w's h-range, so wave w
// polls ONLY slice w's exchange words (sentinel 0x7F7F, relaxed agent
// atomics) and macs immediately -> per-wave straggler decoupling.
// Step = 2 phases: P1 finishB(s-1)[wave sl] || poll+macA(s)
//                  P2 finishA(s)  [wave sl] || poll+macB(s)
// Each store has a full phase in flight before partners poll it.
// ---------------------------------------------------------------------------
__global__ __launch_bounds__(512, 2)
void ltc_scan5(const int* __restrict__ q, const int* __restrict__ r,
               const float* __restrict__ emb_proj, const float* __restrict__ Wh,
               const float* __restrict__ tau, unsigned short* __restrict__ hs_bf) {
    __shared__ float hfA[512], hfB[512], psA[512], psB[512];
    __shared__ int idA[512], idB[512];

    const int tid  = threadIdx.x;
    const int sl   = blockIdx.x >> 5;     // slice: owns h rows sl*64..+63
    const int bp   = blockIdx.x & 31;
    const int bA   = bp * 2, bB = bA + 1;
    const int lane = tid & 63;
    const int w    = tid >> 6;            // wave = k-chunk = partner slice

    // W chunk -> regs: row sl*64+lane, cols w*64..+63 (fp32)
    float4 wr_[16];
    {
        const float* wrow = Wh + (size_t)(sl * 64 + lane) * 512 + w * 64;
        #pragma unroll
        for (int i = 0; i < 16; ++i) wr_[i] = ((const float4*)wrow)[i];
    }

    hfA[tid] = 0.f; hfB[tid] = 0.f;
    idA[tid] = q[bA * SEQ + tid] + NUM_C * r[bA * SEQ + tid];
    idB[tid] = q[bB * SEQ + tid] + NUM_C * r[bB * SEQ + tid];

    const bool fin = (w == sl);           // finish-duty wave (no polling)
    float rtau = 0.f, hA = 0.f, hB = 0.f, embA = 0.f, embB = 0.f;
    if (fin) rtau = 1.0f / tau[sl * 64 + lane];

    unsigned* hswA = (unsigned*)(hs_bf + (size_t)bA * SEQ * HID);
    unsigned* hswB = (unsigned*)(hs_bf + (size_t)bB * SEQ * HID);
    __syncthreads();

    if (fin) {
        embA = emb_proj[(size_t)idA[0] * HID + sl * 64 + lane];
        embB = emb_proj[(size_t)idB[0] * HID + sl * 64 + lane];
    }

    for (int s = 0; s < SEQ; ++s) {
        // ---------- P1: finishB(s-1) [fin] ; poll+mac A(s) [others] ----------
        if (fin) {
            if (s > 0) {
                float pre = embB;
                #pragma unroll
                for (int m = 0; m < 8; ++m) pre += psB[m * 64 + lane];
                float hn = hB + (ftanh(pre) - hB) * rtau;
                hB = hn;
                hfB[sl * 64 + lane] = hn;
                unsigned us = f2bf(hn);
                unsigned ot = (unsigned)__shfl_xor((int)us, 1);
                if (!(lane & 1))
                    __hip_atomic_store(&hswB[(s - 1) * 256 + sl * 32 + (lane >> 1)],
                                       us | (ot << 16), __ATOMIC_RELAXED,
                                       __HIP_MEMORY_SCOPE_AGENT);
                embB = emb_proj[(size_t)idB[s] * HID + sl * 64 + lane]; // for finishB(s)
            }
        } else if (s > 0 && lane < 32) {
            unsigned* ap = &hswA[(s - 1) * 256 + w * 32 + lane];
            unsigned word = __hip_atomic_load(ap, __ATOMIC_RELAXED, __HIP_MEMORY_SCOPE_AGENT);
            while ((word & 0xffffu) == 0x7f7fu) {
                __builtin_amdgcn_s_sleep(1);
                word = __hip_atomic_load(ap, __ATOMIC_RELAXED, __HIP_MEMORY_SCOPE_AGENT);
            }
            float2 hv; hv.x = uaf(word << 16); hv.y = uaf(word & 0xffff0000u);
            *(float2*)&hfA[w * 64 + 2 * lane] = hv;
        }
        {   // mac A: wave w uses only hfA[w*64..+63] (own range)
            const float4* hv4 = (const float4*)(hfA + w * 64);
            float a0 = 0.f, a1 = 0.f, a2 = 0.f, a3 = 0.f;
            #pragma unroll
            for (int i = 0; i < 16; ++i) {
                float4 hv = hv4[i];
                a0 += wr_[i].x * hv.x; a1 += wr_[i].y * hv.y;
                a2 += wr_[i].z * hv.z; a3 += wr_[i].w * hv.w;
            }
            psA[w * 64 + lane] = (a0 + a1) + (a2 + a3);
        }
        __syncthreads();

        // ---------- P2: finishA(s) [fin] ; poll+mac B(s) [others] ----------
        if (fin) {
            float pre = embA;
            #pragma unroll
            for (int m = 0; m < 8; ++m) pre += psA[m * 64 + lane];
            float hn = hA + (ftanh(pre) - hA) * rtau;
            hA = hn;
            hfA[sl * 64 + lane] = hn;
            unsigned us = f2bf(hn);
            unsigned ot = (unsigned)__shfl_xor((int)us, 1);
            if (!(lane & 1))
                __hip_atomic_store(&hswA[s * 256 + sl * 32 + (lane >> 1)],
                                   us | (ot << 16), __ATOMIC_RELAXED,
                                   __HIP_MEMORY_SCOPE_AGENT);
            if (s + 1 < SEQ)
                embA = emb_proj[(size_t)idA[s + 1] * HID + sl * 64 + lane];
        } else if (s > 0 && lane < 32) {
            unsigned* ap = &hswB[(s - 1) * 256 + w * 32 + lane];
            unsigned word = __hip_atomic_load(ap, __ATOMIC_RELAXED, __HIP_MEMORY_SCOPE_AGENT);
            while ((word & 0xffffu) == 0x7f7fu) {
                __builtin_amdgcn_s_sleep(1);
                word = __hip_atomic_load(ap, __ATOMIC_RELAXED, __HIP_MEMORY_SCOPE_AGENT);
            }
            float2 hv; hv.x = uaf(word << 16); hv.y = uaf(word & 0xffff0000u);
            *(float2*)&hfB[w * 64 + 2 * lane] = hv;
        }
        {   // mac B
            const float4* hv4 = (const float4*)(hfB + w * 64);
            float a0 = 0.f, a1 = 0.f, a2 = 0.f, a3 = 0.f;
            #pragma unroll
            for (int i = 0; i < 16; ++i) {
                float4 hv = hv4[i];
                a0 += wr_[i].x * hv.x; a1 += wr_[i].y * hv.y;
                a2 += wr_[i].z * hv.z; a3 += wr_[i].w * hv.w;
            }
            psB[w * 64 + lane] = (a0 + a1) + (a2 + a3);
        }
        __syncthreads();
    }

    // epilogue: finishB(SEQ-1)
    if (fin) {
        float pre = embB;
        #pragma unroll
        for (int m = 0; m < 8; ++m) pre += psB[m * 64 + lane];
        float hn = hB + (ftanh(pre) - hB) * rtau;
        unsigned us = f2bf(hn);
        unsigned ot = (unsigned)__shfl_xor((int)us, 1);
        if (!(lane & 1))
            __hip_atomic_store(&hswB[(SEQ - 1) * 256 + sl * 32 + (lane >> 1)],
                               us | (ot << 16), __ATOMIC_RELAXED,
                               __HIP_MEMORY_SCOPE_AGENT);
    }
}

// ---------------------------------------------------------------------------
// Output GEMM: y = sigmoid(hs_bf @ Wo_bf^T + Wo_b), bf16 MFMA 16x16x32.
// ---------------------------------------------------------------------------
__global__ __launch_bounds__(256)
void gemm_out_bf16(const unsigned short* __restrict__ A,   // [M][512]
                   const unsigned short* __restrict__ B,   // [1024][512]
                   const float* __restrict__ bias,
                   float* __restrict__ C, int M) {
    __shared__ __align__(16) unsigned short As[128 * 32];
    __shared__ __align__(16) unsigned short Bs[128 * 32];

    const int tid = threadIdx.x;
    const int n0 = blockIdx.x * 128;
    const int m0 = blockIdx.y * 128;
    const int w  = tid >> 6;
    const int l  = tid & 63;
    const int wr = w >> 1, wc = w & 1;
    const int lr = l & 15;
    const int lq = l >> 4;

    f32x4 acc[4][4];
    #pragma unroll
    for (int i = 0; i < 4; ++i)
        #pragma unroll
        for (int jn = 0; jn < 4; ++jn)
            acc[i][jn] = (f32x4){0.f, 0.f, 0.f, 0.f};

    for (int k0 = 0; k0 < 512; k0 += 32) {
        #pragma unroll
        for (int p = 0; p < 2; ++p) {
            int flat = p * 256 + tid;
            int row  = flat >> 2;
            int c4   = flat & 3;
            *(uint4*)&As[row * 32 + c4 * 8] =
                *(const uint4*)&A[(size_t)(m0 + row) * 512 + k0 + c4 * 8];
            *(uint4*)&Bs[row * 32 + c4 * 8] =
                *(const uint4*)&B[(size_t)(n0 + row) * 512 + k0 + c4 * 8];
        }
        __syncthreads();

        bf16x8 af[4], bf[4];
        #pragma unroll
        for (int mf = 0; mf < 4; ++mf)
            af[mf] = *(const bf16x8*)&As[(wr * 64 + mf * 16 + lr) * 32 + lq * 8];
        #pragma unroll
        for (int nf = 0; nf < 4; ++nf)
            bf[nf] = *(const bf16x8*)&Bs[(wc * 64 + nf * 16 + lr) * 32 + lq * 8];

        #pragma unroll
        for (int mf = 0; mf < 4; ++mf)
            #pragma unroll
            for (int nf = 0; nf < 4; ++nf)
                acc[mf][nf] = __builtin_amdgcn_mfma_f32_16x16x32_bf16(
                    af[mf], bf[nf], acc[mf][nf], 0, 0, 0);
        __syncthreads();
    }

    #pragma unroll
    for (int mf = 0; mf < 4; ++mf) {
        #pragma unroll
        for (int nf = 0; nf < 4; ++nf) {
            int col = n0 + wc * 64 + nf * 16 + lr;
            float bb = bias[col];
            #pragma unroll
            for (int reg = 0; reg < 4; ++reg) {
                int rowm = m0 + wr * 64 + mf * 16 + lq * 4 + reg;
                float v = acc[mf][nf][reg] + bb;
                C[(size_t)rowm * 1024 + col] = 1.0f / (1.0f + expf(-v));
            }
        }
    }
}

// ---------------------------------------------------------------------------
extern "C" void kernel_launch(void* const* d_in, const int* in_sizes, int n_in,
                              void* d_out, int out_size, void* d_ws, size_t ws_size,
                              hipStream_t stream) {
    const int*   q    = (const int*)d_in[0];
    const int*   r    = (const int*)d_in[1];
    const float* emb  = (const float*)d_in[2];
    const float* Wh_w = (const float*)d_in[3];
    const float* Wh_b = (const float*)d_in[4];
    const float* Wx_w = (const float*)d_in[5];
    const float* Wx_b = (const float*)d_in[6];
    const float* tau  = (const float*)d_in[7];
    const float* Wo_w = (const float*)d_in[8];
    const float* Wo_b = (const float*)d_in[9];
    float* out = (float*)d_out;

    char* ws = (char*)d_ws;
    float*          emb_proj = (float*)ws;                                        // 4 MiB
    unsigned short* Wobf     = (unsigned short*)(ws + (4u << 20));                // 1 MiB
    unsigned short* hs_bf    = (unsigned short*)(ws + (5u << 20));                // 32 MiB

    // sentinel-fill hs (0x7F7F halfwords unreachable for |h|<=1 bf16)
    hipMemsetAsync(hs_bf, 0x7F, (size_t)BATCH * SEQ * HID * 2, stream);

    // Wo -> bf16 for the MFMA output GEMM
    f32_to_bf16<<<(1024 * 512) / 256, 256, 0, stream>>>(Wo_w, Wobf, 1024 * 512);

    // emb_proj = emb @ Wx^T + Wx_b + Wh_b (2048 distinct interaction rows)
    gemm_nt_f32<<<dim3(512 / 64, 2048 / 64), 256, 0, stream>>>(
        emb, Wx_w, emb_proj, 2048, 512, 512, Wx_b, Wh_b);

    // recurrence: 256 blocks (8 slices x 32 batch-pairs), static 12KB LDS
    ltc_scan5<<<256, 512, 0, stream>>>(q, r, emb_proj, Wh_w, tau, hs_bf);

    // y = sigmoid(hs @ Wo^T + Wo_b) via bf16 MFMA
    gemm_out_bf16<<<dim3(1024 / 128, (BATCH * SEQ) / 128), 256, 0, stream>>>(
        hs_bf, Wobf, Wo_b, out, BATCH * SEQ);
}